// Round 11
// baseline (76.699 us; speedup 1.0000x reference)
//
#include <hip/hip_runtime.h>
#include <hip/hip_bf16.h>

#define BATCH 8
#define SEQ   2048
#define DMODEL 1024
#define HD    64

typedef __attribute__((ext_vector_type(8))) short bf16x8;
typedef __attribute__((ext_vector_type(4))) float f32x4;
typedef __attribute__((ext_vector_type(4))) int int4v;
typedef __attribute__((ext_vector_type(2))) unsigned uint2v;
typedef unsigned int u32;

__device__ inline unsigned short f2bf(float f) {
    unsigned u = __builtin_bit_cast(unsigned, f);
    unsigned r = (u + 0x7FFFu + ((u >> 16) & 1u)) >> 16;  // RTNE
    return (unsigned short)r;
}

__device__ inline unsigned cvtpk(float lo, float hi) {
    unsigned r;
    asm("v_cvt_pk_bf16_f32 %0, %1, %2" : "=v"(r) : "v"(lo), "v"(hi));
    return r;
}

// async global->LDS, 16B per lane; LDS dest must be linear (base + lane*16)
__device__ inline void gl_lds16(const void* g, void* l) {
    __builtin_amdgcn_global_load_lds(
        (const __attribute__((address_space(1))) u32*)g,
        (__attribute__((address_space(3))) u32*)l, 16, 0, 0);
}

// ---------------------------------------------------------------------------
// Kernel 1: weights -> fragment-major bf16 layout.
// WFrag[f][t][s][lg][ln][e] (f=p*4+n, t=k/64, s=(k/32)&1, e=k&7):
//   element = W_p[k = t*64+s*32+lg*8+e][h = n*16+ln]
// ---------------------------------------------------------------------------
__global__ void prep_w(const float* __restrict__ Wq, const float* __restrict__ Wk,
                       const float* __restrict__ Wv, unsigned short* __restrict__ WFrag) {
    __shared__ float tt[64][65];
    int p = blockIdx.x >> 4;
    int t = blockIdx.x & 15;
    int k0 = t * 64;
    const float* W = (p == 0) ? Wq : (p == 1) ? Wk : Wv;
    int tid = threadIdx.x;
#pragma unroll
    for (int j = 0; j < 16; j++) {
        int idx = tid + j * 256;
        int r = idx >> 6, c = idx & 63;
        tt[r][c] = W[(size_t)(k0 + r) * HD + c];      // coalesced read
    }
    __syncthreads();
#pragma unroll
    for (int gi = 0; gi < 2; gi++) {
        int g = tid * 2 + gi;                         // 512 groups
        int ln = g & 15, lg = (g >> 4) & 3, s = (g >> 6) & 1, n = (g >> 7) & 3;
        union { bf16x8 v; unsigned short u[8]; } pk;
#pragma unroll
        for (int e = 0; e < 8; e++)
            pk.u[e] = f2bf(tt[s * 32 + lg * 8 + e][n * 16 + ln]);
        *(bf16x8*)(WFrag + (((size_t)(p * 4 + n) * 16 + t) * 1024 + s * 512 + lg * 128 + ln * 8)) = pk.v;
    }
}

// ---------------------------------------------------------------------------
// Kernel 2: projections. BM=32, BN=192, grid 512 (2 blocks/CU).
// NO LDS / NO BARRIERS; dynamic K-loop over step-pairs with named even/odd
// register sets (1-deep software pipeline, bounded pressure, static indices).
// Wave = 2 m-frags x 3 n-frags; W fragment-major (1KB contiguous per load).
// ---------------------------------------------------------------------------
__global__ __launch_bounds__(256, 2) void proj_kernel(
    const float* __restrict__ x,
    const float* __restrict__ bq, const float* __restrict__ bk, const float* __restrict__ bv,
    const unsigned short* __restrict__ WFrag,
    unsigned short* __restrict__ Q, unsigned short* __restrict__ K,
    unsigned short* __restrict__ VT) {

    int tid = threadIdx.x;
    int w = tid >> 6, lane = tid & 63;
    int lg = lane >> 4, ln = lane & 15;
    int m0 = blockIdx.x * 32;

    const unsigned short* wbase[3];
#pragma unroll
    for (int j = 0; j < 3; j++)
        wbase[j] = WFrag + (size_t)(w * 3 + j) * 16384 + lane * 8;

    const float* xr0 = x + (size_t)(m0 + ln) * DMODEL + lg * 8;
    const float* xr1 = x + (size_t)(m0 + 16 + ln) * DMODEL + lg * 8;

    f32x4 acc[2][3];
#pragma unroll
    for (int m = 0; m < 2; m++)
#pragma unroll
        for (int j = 0; j < 3; j++) acc[m][j] = (f32x4){0.f, 0.f, 0.f, 0.f};

    bf16x8 bA[6], bB[6];
    f32x4 xA[8], xB[8];

    auto LB = [&](bf16x8* d, int t) {
#pragma unroll
        for (int s = 0; s < 2; s++)
#pragma unroll
            for (int j = 0; j < 3; j++)
                d[s * 3 + j] = *(const bf16x8*)(wbase[j] + t * 1024 + s * 512);
    };
    auto LX = [&](f32x4* d, int t) {
        int k0 = t * 64;
        d[0] = *(const f32x4*)(xr0 + k0);      d[1] = *(const f32x4*)(xr0 + k0 + 4);
        d[2] = *(const f32x4*)(xr1 + k0);      d[3] = *(const f32x4*)(xr1 + k0 + 4);
        d[4] = *(const f32x4*)(xr0 + k0 + 32); d[5] = *(const f32x4*)(xr0 + k0 + 36);
        d[6] = *(const f32x4*)(xr1 + k0 + 32); d[7] = *(const f32x4*)(xr1 + k0 + 36);
    };
    auto CP = [&](const f32x4* xd, const bf16x8* bd) {
#pragma unroll
        for (int s = 0; s < 2; s++) {
            union { bf16x8 v; unsigned u[4]; } a0, a1;
            a0.u[0] = cvtpk(xd[s * 4 + 0][0], xd[s * 4 + 0][1]);
            a0.u[1] = cvtpk(xd[s * 4 + 0][2], xd[s * 4 + 0][3]);
            a0.u[2] = cvtpk(xd[s * 4 + 1][0], xd[s * 4 + 1][1]);
            a0.u[3] = cvtpk(xd[s * 4 + 1][2], xd[s * 4 + 1][3]);
            a1.u[0] = cvtpk(xd[s * 4 + 2][0], xd[s * 4 + 2][1]);
            a1.u[1] = cvtpk(xd[s * 4 + 2][2], xd[s * 4 + 2][3]);
            a1.u[2] = cvtpk(xd[s * 4 + 3][0], xd[s * 4 + 3][1]);
            a1.u[3] = cvtpk(xd[s * 4 + 3][2], xd[s * 4 + 3][3]);
#pragma unroll
            for (int j = 0; j < 3; j++) {
                acc[0][j] = __builtin_amdgcn_mfma_f32_16x16x32_bf16(a0.v, bd[s * 3 + j], acc[0][j], 0, 0, 0);
                acc[1][j] = __builtin_amdgcn_mfma_f32_16x16x32_bf16(a1.v, bd[s * 3 + j], acc[1][j], 0, 0, 0);
            }
        }
    };

    LX(xA, 0);
    LB(bA, 0);
#pragma unroll 1
    for (int t = 0; t < 16; t += 2) {
        LX(xB, t + 1);
        LB(bB, t + 1);
        CP(xA, bA);
        if (t + 2 < 16) {
            LX(xA, t + 2);
            LB(bA, t + 2);
        }
        CP(xB, bB);
    }

    // epilogue: wave owns 3 n-frags over 32 m-rows
#pragma unroll
    for (int j = 0; j < 3; j++) {
        int f = w * 3 + j;
        int p = f >> 2, n = f & 3;
        int col = n * 16 + ln;
        const float* bias = (p == 0) ? bq : (p == 1) ? bk : bv;
        float bb = bias[col];
#pragma unroll
        for (int m = 0; m < 2; m++) {
#pragma unroll
            for (int r = 0; r < 4; r++) {
                float v = acc[m][j][r] + bb;
                int grow = m0 + m * 16 + lg * 4 + r;
                if (p == 0)      Q[(size_t)grow * HD + col] = f2bf(v);
                else if (p == 1) K[(size_t)grow * HD + col] = f2bf(v);
                else {
                    int b2 = grow >> 11, srow = grow & (SEQ - 1);
                    VT[((size_t)b2 * HD + col) * SEQ + srow] = f2bf(v);
                }
            }
        }
    }
}

// ---------------------------------------------------------------------------
// Kernel 3: flash attention, keys split 4x across blocks. 40KB LDS ->
// 4 blocks/CU. Mask loaded per-tile as int4 from global.
// Partials (bf16 O, f32 m/l) to workspace.  (proven 55.6us version, unchanged)
// ---------------------------------------------------------------------------
__device__ inline void stage_tile(int tid, const unsigned short* Kb, const unsigned short* VTb,
                                  int kt, unsigned short* kbuf, unsigned short* vbuf) {
#pragma unroll
    for (int i = 0; i < 2; i++) {
        int d = tid * 16 + i * 4096;
        int row = d >> 7, slot = (d >> 4) & 7;
        const unsigned short* src = Kb + (size_t)(kt + row) * HD + ((slot ^ (row & 7)) << 3);
        gl_lds16(src, (char*)kbuf + d);
    }
#pragma unroll
    for (int i = 0; i < 2; i++) {
        int d = tid * 16 + i * 4096;
        int row = d >> 7, slot = (d >> 4) & 7;
        const unsigned short* src = VTb + (size_t)row * SEQ + kt + ((slot ^ (row & 7)) << 3);
        gl_lds16(src, (char*)vbuf + d);
    }
}

__global__ __launch_bounds__(256, 4) void attn_kernel(
    const unsigned short* __restrict__ Q, const unsigned short* __restrict__ K,
    const unsigned short* __restrict__ VT, const int* __restrict__ mask,
    float* __restrict__ out,
    unsigned short* __restrict__ Op, float* __restrict__ Mp, float* __restrict__ Lp,
    int nsplit) {

    __shared__ __align__(16) unsigned short Kls[2][64 * 64];   // 16KB
    __shared__ __align__(16) unsigned short Vls[2][64 * 64];   // 16KB
    __shared__ __align__(16) unsigned short plds_[4][16 * 64]; // 8KB

    int tid = threadIdx.x;
    int w = tid >> 6, lane = tid & 63;
    int lg = lane >> 4, ln = lane & 15;
    int b = blockIdx.y;
    int kh = blockIdx.z;
    int q0 = blockIdx.x * 64 + w * 16;
    int ntiles = 32 / nsplit;
    int kt0 = kh * ntiles * 64;

    const float SC = 0.125f * 1.44269504088896f;

    const int* mb = mask + b * SEQ;

    bf16x8 qf[2];
    {
        const unsigned short* qptr = Q + ((size_t)b * SEQ + q0 + ln) * HD + lg * 8;
        qf[0] = *(const bf16x8*)(qptr);
        qf[1] = *(const bf16x8*)(qptr + 32);
    }

    f32x4 o[4];
#pragma unroll
    for (int n = 0; n < 4; n++) o[n] = (f32x4){0.f, 0.f, 0.f, 0.f};
    float mrun = -1e38f, lrun = 0.f;

    const unsigned short* Kb = K + (size_t)b * SEQ * HD;
    const unsigned short* VTb = VT + (size_t)b * HD * SEQ;

    unsigned short* kcur = &Kls[0][0]; unsigned short* knx = &Kls[1][0];
    unsigned short* vcur = &Vls[0][0]; unsigned short* vnx = &Vls[1][0];
    char* pl = (char*)&plds_[w][0];
    const int swz = (ln & 7) << 4;

    stage_tile(tid, Kb, VTb, kt0, kcur, vcur);
    __syncthreads();

#pragma unroll 2
    for (int tt = 0; tt < ntiles; ++tt) {
        int kt = kt0 + tt * 64;
        if (tt < ntiles - 1) stage_tile(tid, Kb, VTb, kt + 64, knx, vnx);

        int4v mi[4];
#pragma unroll
        for (int n = 0; n < 4; ++n)
            mi[n] = *(const int4v*)(mb + kt + n * 16 + lg * 4);

        f32x4 st[4];
        const char* kb = (const char*)kcur;
        __builtin_amdgcn_s_setprio(1);
#pragma unroll
        for (int n = 0; n < 4; ++n) {
            int rb = (n * 16 + ln) * 128;
            bf16x8 ka0 = *(const bf16x8*)(kb + ((rb + lg * 16) ^ swz));
            bf16x8 ka1 = *(const bf16x8*)(kb + ((rb + 64 + lg * 16) ^ swz));
            f32x4 z = (f32x4){0.f, 0.f, 0.f, 0.f};
            st[n] = __builtin_amdgcn_mfma_f32_16x16x32_bf16(ka0, qf[0], z, 0, 0, 0);
            st[n] = __builtin_amdgcn_mfma_f32_16x16x32_bf16(ka1, qf[1], st[n], 0, 0, 0);
        }
        __builtin_amdgcn_s_setprio(0);

#pragma unroll
        for (int n = 0; n < 4; ++n)
#pragma unroll
            for (int r = 0; r < 4; ++r)
                st[n][r] = fmaf(st[n][r], SC, mi[n][r] ? 0.f : -1e30f);

        f32x4 mx = st[0];
#pragma unroll
        for (int n = 1; n < 4; ++n)
#pragma unroll
            for (int r = 0; r < 4; ++r) mx[r] = fmaxf(mx[r], st[n][r]);
        float pmax = fmaxf(fmaxf(mx[0], mx[1]), fmaxf(mx[2], mx[3]));
        pmax = fmaxf(pmax, __shfl_xor(pmax, 16));
        pmax = fmaxf(pmax, __shfl_xor(pmax, 32));

        if (!__all(pmax <= mrun + 8.f)) {
            float mnew = fmaxf(mrun, pmax);
            float corr = exp2f(mrun - mnew);
            mrun = mnew;
            lrun *= corr;
            float c0 = __shfl(corr, lg * 4 + 0);
            float c1 = __shfl(corr, lg * 4 + 1);
            float c2 = __shfl(corr, lg * 4 + 2);
            float c3 = __shfl(corr, lg * 4 + 3);
#pragma unroll
            for (int n = 0; n < 4; ++n) {
                o[n][0] *= c0; o[n][1] *= c1; o[n][2] *= c2; o[n][3] *= c3;
            }
        }

        f32x4 sv = (f32x4){0.f, 0.f, 0.f, 0.f};
#pragma unroll
        for (int n = 0; n < 4; ++n)
#pragma unroll
            for (int r = 0; r < 4; ++r) {
                float pp = exp2f(st[n][r] - mrun);
                st[n][r] = pp;
                sv[r] += pp;
            }
        float ts = (sv[0] + sv[1]) + (sv[2] + sv[3]);
        ts += __shfl_xor(ts, 16);
        ts += __shfl_xor(ts, 32);
        lrun += ts;

#pragma unroll
        for (int n = 0; n < 4; ++n) {
            uint2v ww;
            ww[0] = cvtpk(st[n][0], st[n][1]);
            ww[1] = cvtpk(st[n][2], st[n][3]);
            *(uint2v*)(pl + ((ln * 128 + n * 32 + lg * 8) ^ swz)) = ww;
        }
        asm volatile("s_waitcnt lgkmcnt(0)" ::: "memory");
        __builtin_amdgcn_sched_barrier(0);
        bf16x8 pa0 = *(const bf16x8*)(pl + ((ln * 128 + lg * 16) ^ swz));
        bf16x8 pa1 = *(const bf16x8*)(pl + ((ln * 128 + 64 + lg * 16) ^ swz));

        const char* vb = (const char*)vcur;
        __builtin_amdgcn_s_setprio(1);
#pragma unroll
        for (int n = 0; n < 4; ++n) {
            int rb = (n * 16 + ln) * 128;
            bf16x8 v0 = *(const bf16x8*)(vb + ((rb + lg * 16) ^ swz));
            bf16x8 v1 = *(const bf16x8*)(vb + ((rb + 64 + lg * 16) ^ swz));
            o[n] = __builtin_amdgcn_mfma_f32_16x16x32_bf16(pa0, v0, o[n], 0, 0, 0);
            o[n] = __builtin_amdgcn_mfma_f32_16x16x32_bf16(pa1, v1, o[n], 0, 0, 0);
        }
        __builtin_amdgcn_s_setprio(0);

        __syncthreads();
        unsigned short* tk = kcur; kcur = knx; knx = tk;
        unsigned short* tv = vcur; vcur = vnx; vnx = tv;
    }

    if (nsplit == 1) {
#pragma unroll
        for (int r = 0; r < 4; r++) {
            float Lr = __shfl(lrun, lg * 4 + r);
            float inv = 1.0f / Lr;
            int row = q0 + lg * 4 + r;
#pragma unroll
            for (int n = 0; n < 4; n++)
                out[((size_t)b * SEQ + row) * HD + n * 16 + ln] = o[n][r] * inv;
        }
    } else {
        size_t base = (size_t)kh * BATCH * SEQ * HD;
#pragma unroll
        for (int r = 0; r < 4; r++) {
            int row = q0 + lg * 4 + r;
            size_t gr = (size_t)b * SEQ + row;
#pragma unroll
            for (int n = 0; n < 4; n++)
                Op[base + gr * HD + n * 16 + ln] = f2bf(o[n][r]);
        }
        if (lane < 16) {
            size_t gr = (size_t)b * SEQ + q0 + ln;
            Mp[(size_t)kh * BATCH * SEQ + gr] = mrun;
            Lp[(size_t)kh * BATCH * SEQ + gr] = lrun;
        }
    }
}

// ---------------------------------------------------------------------------
// Kernel 4: combine 4 key-split partials -> out. Thread = 8 cols of one row.
// ---------------------------------------------------------------------------
__global__ __launch_bounds__(256) void combine_kernel(
    const unsigned short* __restrict__ Op, const float* __restrict__ Mp,
    const float* __restrict__ Lp, float* __restrict__ out) {
    int g = blockIdx.x * 256 + threadIdx.x;
    int row = g >> 3;
    int c0 = (g & 7) * 8;
    const int NR = BATCH * SEQ;

    float m[4], l[4];
#pragma unroll
    for (int s = 0; s < 4; s++) {
        m[s] = Mp[(size_t)s * NR + row];
        l[s] = Lp[(size_t)s * NR + row];
    }
    float M = fmaxf(fmaxf(m[0], m[1]), fmaxf(m[2], m[3]));
    float e[4], L = 0.f;
#pragma unroll
    for (int s = 0; s < 4; s++) { e[s] = exp2f(m[s] - M); L += l[s] * e[s]; }
    float inv = 1.0f / L;

    float acc[8] = {0.f, 0.f, 0.f, 0.f, 0.f, 0.f, 0.f, 0.f};
#pragma unroll
    for (int s = 0; s < 4; s++) {
        bf16x8 ov = *(const bf16x8*)(Op + ((size_t)s * NR + row) * HD + c0);
#pragma unroll
        for (int i = 0; i < 8; i++) {
            float f = __builtin_bit_cast(float, ((u32)(unsigned short)ov[i]) << 16);
            acc[i] += f * e[s];
        }
    }
    f32x4 r0, r1;
#pragma unroll
    for (int i = 0; i < 4; i++) { r0[i] = acc[i] * inv; r1[i] = acc[4 + i] * inv; }
    *(f32x4*)(out + (size_t)row * HD + c0) = r0;
    *(f32x4*)(out + (size_t)row * HD + c0 + 4) = r1;
}

// ---------------------------------------------------------------------------
extern "C" void kernel_launch(void* const* d_in, const int* in_sizes, int n_in,
                              void* d_out, int out_size, void* d_ws, size_t ws_size,
                              hipStream_t stream) {
    const float* x  = (const float*)d_in[0];
    const int*   am = (const int*)d_in[1];
    const float* Wq = (const float*)d_in[2];
    const float* bq = (const float*)d_in[3];
    const float* Wk = (const float*)d_in[4];
    const float* bk = (const float*)d_in[5];
    const float* Wv = (const float*)d_in[6];
    const float* bv = (const float*)d_in[7];
    float* out = (float*)d_out;

    unsigned short* ws = (unsigned short*)d_ws;
    unsigned short* Wt  = ws;                               // WFrag, 196608 sh
    unsigned short* Qw  = ws + 3 * HD * DMODEL;
    unsigned short* Kw  = Qw + (size_t)BATCH * SEQ * HD;
    unsigned short* VTw = Kw + (size_t)BATCH * SEQ * HD;
    size_t base_sh = 3 * HD * DMODEL + 3 * (size_t)BATCH * SEQ * HD;
    unsigned short* Op = ws + base_sh;                      // [4][B*S][HD] bf16
    float* Mp = (float*)(Op + 4 * (size_t)BATCH * SEQ * HD);// [4][B*S]
    float* Lp = Mp + 4 * (size_t)BATCH * SEQ;               // [4][B*S]
    size_t need = base_sh * 2 + 4 * (size_t)BATCH * SEQ * HD * 2
                + 8 * (size_t)BATCH * SEQ * 4;

    int nsplit = (ws_size >= need) ? 4 : 1;

    prep_w<<<48, 256, 0, stream>>>(Wq, Wk, Wv, Wt);
    proj_kernel<<<(BATCH * SEQ) / 32, 256, 0, stream>>>(x, bq, bk, bv, Wt, Qw, Kw, VTw);
    attn_kernel<<<dim3(SEQ / 64, BATCH, nsplit), 256, 0, stream>>>(Qw, Kw, VTw, am, out,
                                                                   Op, Mp, Lp, nsplit);
    if (nsplit == 4)
        combine_kernel<<<(BATCH * SEQ * 8) / 256, 256, 0, stream>>>(Op, Mp, Lp, out);
}

// Round 13
// 56.191 us; speedup vs baseline: 1.3650x; 1.3650x over previous
//
#include <hip/hip_runtime.h>
#include <hip/hip_bf16.h>

#define BATCH 8
#define SEQ   2048
#define DMODEL 1024
#define HD    64

typedef __attribute__((ext_vector_type(8))) short bf16x8;
typedef __attribute__((ext_vector_type(4))) float f32x4;
typedef __attribute__((ext_vector_type(4))) int int4v;
typedef __attribute__((ext_vector_type(2))) unsigned uint2v;
typedef unsigned int u32;

__device__ inline unsigned short f2bf(float f) {
    unsigned u = __builtin_bit_cast(unsigned, f);
    unsigned r = (u + 0x7FFFu + ((u >> 16) & 1u)) >> 16;  // RTNE
    return (unsigned short)r;
}

__device__ inline unsigned cvtpk(float lo, float hi) {
    unsigned r;
    asm("v_cvt_pk_bf16_f32 %0, %1, %2" : "=v"(r) : "v"(lo), "v"(hi));
    return r;
}

// async global->LDS, 16B per lane; LDS dest must be linear (base + lane*16)
__device__ inline void gl_lds16(const void* g, void* l) {
    __builtin_amdgcn_global_load_lds(
        (const __attribute__((address_space(1))) u32*)g,
        (__attribute__((address_space(3))) u32*)l, 16, 0, 0);
}

// ---------------------------------------------------------------------------
// Kernel 1: weights -> fragment-major bf16 layout.
// WFrag[f][t][s][lg][ln][e] (f=p*4+n, t=k/64, s=(k/32)&1, e=k&7):
//   element = W_p[k = t*64+s*32+lg*8+e][h = n*16+ln]
// ---------------------------------------------------------------------------
__global__ void prep_w(const float* __restrict__ Wq, const float* __restrict__ Wk,
                       const float* __restrict__ Wv, unsigned short* __restrict__ WFrag) {
    __shared__ float tt[64][65];
    int p = blockIdx.x >> 4;
    int t = blockIdx.x & 15;
    int k0 = t * 64;
    const float* W = (p == 0) ? Wq : (p == 1) ? Wk : Wv;
    int tid = threadIdx.x;
#pragma unroll
    for (int j = 0; j < 16; j++) {
        int idx = tid + j * 256;
        int r = idx >> 6, c = idx & 63;
        tt[r][c] = W[(size_t)(k0 + r) * HD + c];      // coalesced read
    }
    __syncthreads();
#pragma unroll
    for (int gi = 0; gi < 2; gi++) {
        int g = tid * 2 + gi;                         // 512 groups
        int ln = g & 15, lg = (g >> 4) & 3, s = (g >> 6) & 1, n = (g >> 7) & 3;
        union { bf16x8 v; unsigned short u[8]; } pk;
#pragma unroll
        for (int e = 0; e < 8; e++)
            pk.u[e] = f2bf(tt[s * 32 + lg * 8 + e][n * 16 + ln]);
        *(bf16x8*)(WFrag + (((size_t)(p * 4 + n) * 16 + t) * 1024 + s * 512 + lg * 128 + ln * 8)) = pk.v;
    }
}

// ---------------------------------------------------------------------------
// Kernel 2: projections. BM=32, BN=192, BK=128 (8 barriers), grid 512
// (2 blocks/CU). All global loads issued at the TOP of each phase so the
// compute body hides their latency before the __syncthreads drain.
// x: f32 global->reg (named xA/xB) -> cvt_pk -> 16-slot-swizzled bf16 LDS
// (2 x 8KB dbuf). W: fragment-major global->reg, distance-1 prefetch into
// the non-consumed named set (bA/bB). Wave = 2 m-frags x 3 n-frags.
// ---------------------------------------------------------------------------
__global__ __launch_bounds__(256, 2) void proj_kernel(
    const float* __restrict__ x,
    const float* __restrict__ bq, const float* __restrict__ bk, const float* __restrict__ bv,
    const unsigned short* __restrict__ WFrag,
    unsigned short* __restrict__ Q, unsigned short* __restrict__ K,
    unsigned short* __restrict__ VT) {

    __shared__ __align__(16) unsigned short Xls[2][32 * 128];  // bf16, 8KB each

    int tid = threadIdx.x;
    int w = tid >> 6, lane = tid & 63;
    int lg = lane >> 4, ln = lane & 15;
    int m0 = blockIdx.x * 32;

    const unsigned short* wbase[3];
#pragma unroll
    for (int j = 0; j < 3; j++)
        wbase[j] = WFrag + (size_t)(w * 3 + j) * 16384 + lane * 8;

    f32x4 acc[2][3];
#pragma unroll
    for (int m = 0; m < 2; m++)
#pragma unroll
        for (int j = 0; j < 3; j++) acc[m][j] = (f32x4){0.f, 0.f, 0.f, 0.f};

    f32x4 xA[4], xB[4];        // named x reg sets (tile = 32 rows x 128 cols f32)
    bf16x8 bA[12], bB[12];     // named W sets, 12 frags per 128-wide phase

    // x chunk geometry: c = tid + i*256 in [0,1024); row=c>>5, 4-f32 col=(c&31)*4
    auto loadX = [&](f32x4* xr, int tile) {
#pragma unroll
        for (int i = 0; i < 4; i++) {
            int c = tid + i * 256;
            xr[i] = *(const f32x4*)(x + (size_t)(m0 + (c >> 5)) * DMODEL + tile * 128 + (c & 31) * 4);
        }
    };
    // bf16 row = 256B = 16 x 16B slots; slot = (c&31)>>1, half = c&1; XOR row&15
    auto writeX = [&](unsigned short* buf, const f32x4* xr) {
#pragma unroll
        for (int i = 0; i < 4; i++) {
            int c = tid + i * 256;
            int row = c >> 5, cc = c & 31;
            uint2v pk;
            pk[0] = cvtpk(xr[i][0], xr[i][1]);
            pk[1] = cvtpk(xr[i][2], xr[i][3]);
            *(uint2v*)((char*)buf + row * 256 + (((cc >> 1) ^ (row & 15)) << 4) + (c & 1) * 8) = pk;
        }
    };
    // W for 128-wide phase p: K-steps 2p, 2p+1; substep s in 0..3
    auto loadB = [&](bf16x8* d, int ph) {
#pragma unroll
        for (int s = 0; s < 4; s++)
#pragma unroll
            for (int j = 0; j < 3; j++)
                d[s * 3 + j] = *(const bf16x8*)(wbase[j] + (2 * ph + (s >> 1)) * 1024 + (s & 1) * 512);
    };
    auto COMPUTE = [&](const unsigned short* buf, const bf16x8* bd) {
        const char* xb = (const char*)buf;
#pragma unroll
        for (int s = 0; s < 4; s++) {
            bf16x8 a[2];
#pragma unroll
            for (int m = 0; m < 2; m++) {
                int row = m * 16 + ln;
                a[m] = *(const bf16x8*)(xb + row * 256 + ((((s << 2) + lg) ^ (row & 15)) << 4));
            }
#pragma unroll
            for (int j = 0; j < 3; j++) {
                acc[0][j] = __builtin_amdgcn_mfma_f32_16x16x32_bf16(a[0], bd[s * 3 + j], acc[0][j], 0, 0, 0);
                acc[1][j] = __builtin_amdgcn_mfma_f32_16x16x32_bf16(a[1], bd[s * 3 + j], acc[1][j], 0, 0, 0);
            }
        }
    };

    // prologue: tile0 staged, bA=W(0), xB=tile1
    loadX(xA, 0);
    loadB(bA, 0);
    writeX(&Xls[0][0], xA);
    loadX(xB, 1);
    __syncthreads();

#pragma unroll 1
    for (int p = 0; p < 4; p++) {
        // phase even: tile 2p from Xls[0]/bA
        writeX(&Xls[1][0], xB);            // stage tile 2p+1 (xB loaded last phase)
        if (p < 3) loadX(xA, 2 * p + 2);   // issue x globals for tile 2p+2
        loadB(bB, 2 * p + 1);              // issue W globals for tile 2p+1
        COMPUTE(&Xls[0][0], bA);
        __syncthreads();
        // phase odd: tile 2p+1 from Xls[1]/bB
        if (p < 3) {
            writeX(&Xls[0][0], xA);        // stage tile 2p+2
            loadX(xB, 2 * p + 3);          // issue x globals for tile 2p+3
            loadB(bA, 2 * p + 2);          // issue W globals for tile 2p+2
        }
        COMPUTE(&Xls[1][0], bB);
        __syncthreads();
    }

    // epilogue: wave owns 3 n-frags over 32 m-rows
#pragma unroll
    for (int j = 0; j < 3; j++) {
        int f = w * 3 + j;
        int p = f >> 2, n = f & 3;
        int col = n * 16 + ln;
        const float* bias = (p == 0) ? bq : (p == 1) ? bk : bv;
        float bb = bias[col];
#pragma unroll
        for (int m = 0; m < 2; m++) {
#pragma unroll
            for (int r = 0; r < 4; r++) {
                float v = acc[m][j][r] + bb;
                int grow = m0 + m * 16 + lg * 4 + r;
                if (p == 0)      Q[(size_t)grow * HD + col] = f2bf(v);
                else if (p == 1) K[(size_t)grow * HD + col] = f2bf(v);
                else {
                    int b2 = grow >> 11, srow = grow & (SEQ - 1);
                    VT[((size_t)b2 * HD + col) * SEQ + srow] = f2bf(v);
                }
            }
        }
    }
}

// ---------------------------------------------------------------------------
// Kernel 3: flash attention, keys split 4x across blocks. 40KB LDS ->
// 4 blocks/CU. Mask loaded per-tile as int4 from global.
// Partials (bf16 O, f32 m/l) to workspace.  (proven R8 version, unchanged)
// ---------------------------------------------------------------------------
__device__ inline void stage_tile(int tid, const unsigned short* Kb, const unsigned short* VTb,
                                  int kt, unsigned short* kbuf, unsigned short* vbuf) {
#pragma unroll
    for (int i = 0; i < 2; i++) {
        int d = tid * 16 + i * 4096;
        int row = d >> 7, slot = (d >> 4) & 7;
        const unsigned short* src = Kb + (size_t)(kt + row) * HD + ((slot ^ (row & 7)) << 3);
        gl_lds16(src, (char*)kbuf + d);
    }
#pragma unroll
    for (int i = 0; i < 2; i++) {
        int d = tid * 16 + i * 4096;
        int row = d >> 7, slot = (d >> 4) & 7;
        const unsigned short* src = VTb + (size_t)row * SEQ + kt + ((slot ^ (row & 7)) << 3);
        gl_lds16(src, (char*)vbuf + d);
    }
}

__global__ __launch_bounds__(256, 4) void attn_kernel(
    const unsigned short* __restrict__ Q, const unsigned short* __restrict__ K,
    const unsigned short* __restrict__ VT, const int* __restrict__ mask,
    float* __restrict__ out,
    unsigned short* __restrict__ Op, float* __restrict__ Mp, float* __restrict__ Lp,
    int nsplit) {

    __shared__ __align__(16) unsigned short Kls[2][64 * 64];   // 16KB
    __shared__ __align__(16) unsigned short Vls[2][64 * 64];   // 16KB
    __shared__ __align__(16) unsigned short plds_[4][16 * 64]; // 8KB

    int tid = threadIdx.x;
    int w = tid >> 6, lane = tid & 63;
    int lg = lane >> 4, ln = lane & 15;
    int b = blockIdx.y;
    int kh = blockIdx.z;
    int q0 = blockIdx.x * 64 + w * 16;
    int ntiles = 32 / nsplit;
    int kt0 = kh * ntiles * 64;

    const float SC = 0.125f * 1.44269504088896f;

    const int* mb = mask + b * SEQ;

    bf16x8 qf[2];
    {
        const unsigned short* qptr = Q + ((size_t)b * SEQ + q0 + ln) * HD + lg * 8;
        qf[0] = *(const bf16x8*)(qptr);
        qf[1] = *(const bf16x8*)(qptr + 32);
    }

    f32x4 o[4];
#pragma unroll
    for (int n = 0; n < 4; n++) o[n] = (f32x4){0.f, 0.f, 0.f, 0.f};
    float mrun = -1e38f, lrun = 0.f;

    const unsigned short* Kb = K + (size_t)b * SEQ * HD;
    const unsigned short* VTb = VT + (size_t)b * HD * SEQ;

    unsigned short* kcur = &Kls[0][0]; unsigned short* knx = &Kls[1][0];
    unsigned short* vcur = &Vls[0][0]; unsigned short* vnx = &Vls[1][0];
    char* pl = (char*)&plds_[w][0];
    const int swz = (ln & 7) << 4;

    stage_tile(tid, Kb, VTb, kt0, kcur, vcur);
    __syncthreads();

#pragma unroll 2
    for (int tt = 0; tt < ntiles; ++tt) {
        int kt = kt0 + tt * 64;
        if (tt < ntiles - 1) stage_tile(tid, Kb, VTb, kt + 64, knx, vnx);

        int4v mi[4];
#pragma unroll
        for (int n = 0; n < 4; ++n)
            mi[n] = *(const int4v*)(mb + kt + n * 16 + lg * 4);

        f32x4 st[4];
        const char* kb = (const char*)kcur;
        __builtin_amdgcn_s_setprio(1);
#pragma unroll
        for (int n = 0; n < 4; ++n) {
            int rb = (n * 16 + ln) * 128;
            bf16x8 ka0 = *(const bf16x8*)(kb + ((rb + lg * 16) ^ swz));
            bf16x8 ka1 = *(const bf16x8*)(kb + ((rb + 64 + lg * 16) ^ swz));
            f32x4 z = (f32x4){0.f, 0.f, 0.f, 0.f};
            st[n] = __builtin_amdgcn_mfma_f32_16x16x32_bf16(ka0, qf[0], z, 0, 0, 0);
            st[n] = __builtin_amdgcn_mfma_f32_16x16x32_bf16(ka1, qf[1], st[n], 0, 0, 0);
        }
        __builtin_amdgcn_s_setprio(0);

#pragma unroll
        for (int n = 0; n < 4; ++n)
#pragma unroll
            for (int r = 0; r < 4; ++r)
                st[n][r] = fmaf(st[n][r], SC, mi[n][r] ? 0.f : -1e30f);

        f32x4 mx = st[0];
#pragma unroll
        for (int n = 1; n < 4; ++n)
#pragma unroll
            for (int r = 0; r < 4; ++r) mx[r] = fmaxf(mx[r], st[n][r]);
        float pmax = fmaxf(fmaxf(mx[0], mx[1]), fmaxf(mx[2], mx[3]));
        pmax = fmaxf(pmax, __shfl_xor(pmax, 16));
        pmax = fmaxf(pmax, __shfl_xor(pmax, 32));

        if (!__all(pmax <= mrun + 8.f)) {
            float mnew = fmaxf(mrun, pmax);
            float corr = exp2f(mrun - mnew);
            mrun = mnew;
            lrun *= corr;
            float c0 = __shfl(corr, lg * 4 + 0);
            float c1 = __shfl(corr, lg * 4 + 1);
            float c2 = __shfl(corr, lg * 4 + 2);
            float c3 = __shfl(corr, lg * 4 + 3);
#pragma unroll
            for (int n = 0; n < 4; ++n) {
                o[n][0] *= c0; o[n][1] *= c1; o[n][2] *= c2; o[n][3] *= c3;
            }
        }

        f32x4 sv = (f32x4){0.f, 0.f, 0.f, 0.f};
#pragma unroll
        for (int n = 0; n < 4; ++n)
#pragma unroll
            for (int r = 0; r < 4; ++r) {
                float pp = exp2f(st[n][r] - mrun);
                st[n][r] = pp;
                sv[r] += pp;
            }
        float ts = (sv[0] + sv[1]) + (sv[2] + sv[3]);
        ts += __shfl_xor(ts, 16);
        ts += __shfl_xor(ts, 32);
        lrun += ts;

#pragma unroll
        for (int n = 0; n < 4; ++n) {
            uint2v ww;
            ww[0] = cvtpk(st[n][0], st[n][1]);
            ww[1] = cvtpk(st[n][2], st[n][3]);
            *(uint2v*)(pl + ((ln * 128 + n * 32 + lg * 8) ^ swz)) = ww;
        }
        asm volatile("s_waitcnt lgkmcnt(0)" ::: "memory");
        __builtin_amdgcn_sched_barrier(0);
        bf16x8 pa0 = *(const bf16x8*)(pl + ((ln * 128 + lg * 16) ^ swz));
        bf16x8 pa1 = *(const bf16x8*)(pl + ((ln * 128 + 64 + lg * 16) ^ swz));

        const char* vb = (const char*)vcur;
        __builtin_amdgcn_s_setprio(1);
#pragma unroll
        for (int n = 0; n < 4; ++n) {
            int rb = (n * 16 + ln) * 128;
            bf16x8 v0 = *(const bf16x8*)(vb + ((rb + lg * 16) ^ swz));
            bf16x8 v1 = *(const bf16x8*)(vb + ((rb + 64 + lg * 16) ^ swz));
            o[n] = __builtin_amdgcn_mfma_f32_16x16x32_bf16(pa0, v0, o[n], 0, 0, 0);
            o[n] = __builtin_amdgcn_mfma_f32_16x16x32_bf16(pa1, v1, o[n], 0, 0, 0);
        }
        __builtin_amdgcn_s_setprio(0);

        __syncthreads();
        unsigned short* tk = kcur; kcur = knx; knx = tk;
        unsigned short* tv = vcur; vcur = vnx; vnx = tv;
    }

    if (nsplit == 1) {
#pragma unroll
        for (int r = 0; r < 4; r++) {
            float Lr = __shfl(lrun, lg * 4 + r);
            float inv = 1.0f / Lr;
            int row = q0 + lg * 4 + r;
#pragma unroll
            for (int n = 0; n < 4; n++)
                out[((size_t)b * SEQ + row) * HD + n * 16 + ln] = o[n][r] * inv;
        }
    } else {
        size_t base = (size_t)kh * BATCH * SEQ * HD;
#pragma unroll
        for (int r = 0; r < 4; r++) {
            int row = q0 + lg * 4 + r;
            size_t gr = (size_t)b * SEQ + row;
#pragma unroll
            for (int n = 0; n < 4; n++)
                Op[base + gr * HD + n * 16 + ln] = f2bf(o[n][r]);
        }
        if (lane < 16) {
            size_t gr = (size_t)b * SEQ + q0 + ln;
            Mp[(size_t)kh * BATCH * SEQ + gr] = mrun;
            Lp[(size_t)kh * BATCH * SEQ + gr] = lrun;
        }
    }
}

// ---------------------------------------------------------------------------
// Kernel 4: combine 4 key-split partials -> out. Thread = 8 cols of one row.
// ---------------------------------------------------------------------------
__global__ __launch_bounds__(256) void combine_kernel(
    const unsigned short* __restrict__ Op, const float* __restrict__ Mp,
    const float* __restrict__ Lp, float* __restrict__ out) {
    int g = blockIdx.x * 256 + threadIdx.x;
    int row = g >> 3;
    int c0 = (g & 7) * 8;
    const int NR = BATCH * SEQ;

    float m[4], l[4];
#pragma unroll
    for (int s = 0; s < 4; s++) {
        m[s] = Mp[(size_t)s * NR + row];
        l[s] = Lp[(size_t)s * NR + row];
    }
    float M = fmaxf(fmaxf(m[0], m[1]), fmaxf(m[2], m[3]));
    float e[4], L = 0.f;
#pragma unroll
    for (int s = 0; s < 4; s++) { e[s] = exp2f(m[s] - M); L += l[s] * e[s]; }
    float inv = 1.0f / L;

    float acc[8] = {0.f, 0.f, 0.f, 0.f, 0.f, 0.f, 0.f, 0.f};
#pragma unroll
    for (int s = 0; s < 4; s++) {
        bf16x8 ov = *(const bf16x8*)(Op + ((size_t)s * NR + row) * HD + c0);
#pragma unroll
        for (int i = 0; i < 8; i++) {
            float f = __builtin_bit_cast(float, ((u32)(unsigned short)ov[i]) << 16);
            acc[i] += f * e[s];
        }
    }
    f32x4 r0, r1;
#pragma unroll
    for (int i = 0; i < 4; i++) { r0[i] = acc[i] * inv; r1[i] = acc[4 + i] * inv; }
    *(f32x4*)(out + (size_t)row * HD + c0) = r0;
    *(f32x4*)(out + (size_t)row * HD + c0 + 4) = r1;
}

// ---------------------------------------------------------------------------
extern "C" void kernel_launch(void* const* d_in, const int* in_sizes, int n_in,
                              void* d_out, int out_size, void* d_ws, size_t ws_size,
                              hipStream_t stream) {
    const float* x  = (const float*)d_in[0];
    const int*   am = (const int*)d_in[1];
    const float* Wq = (const float*)d_in[2];
    const float* bq = (const float*)d_in[3];
    const float* Wk = (const float*)d_in[4];
    const float* bk = (const float*)d_in[5];
    const float* Wv = (const float*)d_in[6];
    const float* bv = (const float*)d_in[7];
    float* out = (float*)d_out;

    unsigned short* ws = (unsigned short*)d_ws;
    unsigned short* Wt  = ws;                               // WFrag, 196608 sh
    unsigned short* Qw  = ws + 3 * HD * DMODEL;
    unsigned short* Kw  = Qw + (size_t)BATCH * SEQ * HD;
    unsigned short* VTw = Kw + (size_t)BATCH * SEQ * HD;
    size_t base_sh = 3 * HD * DMODEL + 3 * (size_t)BATCH * SEQ * HD;
    unsigned short* Op = ws + base_sh;                      // [4][B*S][HD] bf16
    float* Mp = (float*)(Op + 4 * (size_t)BATCH * SEQ * HD);// [4][B*S]
    float* Lp = Mp + 4 * (size_t)BATCH * SEQ;               // [4][B*S]
    size_t need = base_sh * 2 + 4 * (size_t)BATCH * SEQ * HD * 2
                + 8 * (size_t)BATCH * SEQ * 4;

    int nsplit = (ws_size >= need) ? 4 : 1;

    prep_w<<<48, 256, 0, stream>>>(Wq, Wk, Wv, Wt);
    proj_kernel<<<(BATCH * SEQ) / 32, 256, 0, stream>>>(x, bq, bk, bv, Wt, Qw, Kw, VTw);
    attn_kernel<<<dim3(SEQ / 64, BATCH, nsplit), 256, 0, stream>>>(Qw, Kw, VTw, am, out,
                                                                   Op, Mp, Lp, nsplit);
    if (nsplit == 4)
        combine_kernel<<<(BATCH * SEQ * 8) / 256, 256, 0, stream>>>(Op, Mp, Lp, out);
}